// Round 8
// baseline (139.263 us; speedup 1.0000x reference)
//
#include <hip/hip_runtime.h>
#include <hip/hip_bf16.h>

#define D_DIM 64
#define K_CODES 512

typedef _Float16 half8 __attribute__((ext_vector_type(8)));
typedef float f32x4 __attribute__((ext_vector_type(4)));

typedef __attribute__((address_space(1))) const char gl_char;
typedef __attribute__((address_space(3))) char lds_char;

// ws layout: ee f32[512] @0 ; ET f32[512*64] @2048 B ; Bimg f16[512*64*2] @133120 B
#define WS_EE_OFF 0
#define WS_ET_OFF 2048
#define WS_BIMG_OFF 133120
#define WS_NEEDED (133120 + 131072)

// ---------------- prep: ee, ET (gather layout), Bimg (frag-ordered f16 hi/lo) ------------
__global__ __launch_bounds__(256) void vq3_prep(const float* __restrict__ E,
                                                float* __restrict__ ee,
                                                float* __restrict__ ET,
                                                _Float16* __restrict__ Bimg) {
    int k = blockIdx.x * 256 + threadIdx.x;
    if (k >= K_CODES) return;
    const int t = k >> 4, n = k & 15;
    float s = 0.f;
#pragma unroll
    for (int d = 0; d < D_DIM; ++d) {
        float e = E[(size_t)d * K_CODES + k];
        s = fmaf(e, e, s);
        ET[(size_t)k * D_DIM + d] = e;
        _Float16 hi = (_Float16)e;
        _Float16 lo = (_Float16)((e - (float)hi) * 2048.0f);
        int ks = d >> 5, g = (d >> 3) & 3, j = d & 7;
        size_t base = ((size_t)(t * 4) * 4 + (size_t)g) * 128 + n * 8 + j;
        Bimg[base + (size_t)ks * 512] = hi;          // part = ks
        Bimg[base + (size_t)(2 + ks) * 512] = lo;    // part = 2+ks
    }
    ee[k] = s;
}

// ---------------- main: whole codebook in LDS + 2-stage software-pipelined K-loop --------
// Rounds 2-7 all hit ~52-57 us / MfmaUtil ~17% regardless of B path: within a wave, the
// score VALU depends on the SAME tile's MFMAs, so MFMA-issue and VALU phases serialize
// (931 cyc matrix + ~500 cyc VALU per SIMD-iteration, measured 1688). Fix: score tile t-1
// (long complete) while issuing tile t's MFMAs -- two accumulator stages, interleaved
// per-rt. ee is folded into the hh accumulator INIT (C operand = -ee/2), so score is
// u = hh + 2^-11*cr, argMAX, 4 VALU/elem. Loss computed from A-frags (x ~ hi + lo*2^-11).
#define MFMA16 __builtin_amdgcn_mfma_f32_16x16x32_f16

__global__ __launch_bounds__(512, 2) void vq8_main(
        const float* __restrict__ x, const float* __restrict__ ee,
        const float* __restrict__ ET, const _Float16* __restrict__ Bimg,
        float* __restrict__ out_q, float* __restrict__ out_loss, float loss_scale) {
    __shared__ __align__(16) _Float16 Bs[65536];     // 128 KB: full frag-ordered codebook
    __shared__ float ee_s[K_CODES];
    __shared__ int idx_s[512];
    __shared__ float wsum_s[8];

    const int tid = threadIdx.x;
    const int l = tid & 63;            // lane
    const int w = tid >> 6;            // wave (0..7)
    const int g = l >> 4;              // k-group quad
    const int n = l & 15;              // A row / B col within tile
    const int bt0 = blockIdx.x * 512;  // block token base
    const int t0 = bt0 + w * 64;       // wave token base (64 tokens/wave)

    // ---- stage ALL of Bimg into LDS (wave-uniform base + lane*16 per call)
    {
        const char* gB = (const char*)Bimg;
#pragma unroll
        for (int i = 0; i < 16; ++i) {
            const int woff = (i * 512 + w * 64) * 16;
            __builtin_amdgcn_global_load_lds((gl_char*)(gB + woff + l * 16),
                                             (lds_char*)((char*)Bs + woff), 16, 0, 0);
        }
    }

    // ---- A fragments: 4 row-tiles x 2 k-steps, hi and lo(x2^11), in regs all kernel
    half8 Ahi[4][2], Alo[4][2];
#pragma unroll
    for (int rt = 0; rt < 4; ++rt) {
#pragma unroll
        for (int ks = 0; ks < 2; ++ks) {
            const float4* xp = (const float4*)(x + (size_t)(t0 + rt * 16 + n) * D_DIM + ks * 32 + g * 8);
            float4 a = xp[0], b = xp[1];
            float va[8] = {a.x, a.y, a.z, a.w, b.x, b.y, b.z, b.w};
            half8 h, lo;
#pragma unroll
            for (int j = 0; j < 8; ++j) {
                _Float16 hj = (_Float16)va[j];
                h[j] = hj;
                lo[j] = (_Float16)((va[j] - (float)hj) * 2048.0f);
            }
            Ahi[rt][ks] = h;
            Alo[rt][ks] = lo;
        }
    }

    // ---- ee -> LDS
    if (tid < K_CODES) ee_s[tid] = ee[tid];

    // ---- running argMAX state (u = dot - ee/2; argmax u == argmin dist)
    float bu[4][4];
    int bi[4][4];
#pragma unroll
    for (int i = 0; i < 4; ++i)
#pragma unroll
        for (int r = 0; r < 4; ++r) { bu[i][r] = -3.4e38f; bi[i][r] = 0; }

    __syncthreads();   // drains staging DMA + ee_s. Only barrier before epilogue.

    const _Float16* bbase = Bs + (size_t)g * 128 + n * 8;

#define LOADB(T, B0, B1, B2, B3, EV)                                   \
    {   const _Float16* bp = bbase + (size_t)(T) * 2048;               \
        B0 = *(const half8*)(bp + 0 * 512);                            \
        B1 = *(const half8*)(bp + 1 * 512);                            \
        B2 = *(const half8*)(bp + 2 * 512);                            \
        B3 = *(const half8*)(bp + 3 * 512);                            \
        EV = ee_s[(T) * 16 + n]; }

    // hh chain seeded with C = -ee/2 (folds ee into the accumulator)
#define MFMA_RT(rt, HH, CR, B0, B1, B2, B3, EV)                        \
    {   float iv_ = -0.5f * (EV);                                      \
        f32x4 ci_; ci_[0] = iv_; ci_[1] = iv_; ci_[2] = iv_; ci_[3] = iv_; \
        f32x4 cz_ = (f32x4){0.f, 0.f, 0.f, 0.f};                       \
        HH[rt] = MFMA16(Ahi[rt][0], B0, ci_, 0, 0, 0);                 \
        HH[rt] = MFMA16(Ahi[rt][1], B1, HH[rt], 0, 0, 0);              \
        CR[rt] = MFMA16(Ahi[rt][0], B2, cz_, 0, 0, 0);                 \
        CR[rt] = MFMA16(Ahi[rt][1], B3, CR[rt], 0, 0, 0);              \
        CR[rt] = MFMA16(Alo[rt][0], B0, CR[rt], 0, 0, 0);              \
        CR[rt] = MFMA16(Alo[rt][1], B1, CR[rt], 0, 0, 0); }

    // strict > with ascending code traversal keeps lowest index on ties
#define SCORE_RT(rt, HH, CR, CODE)                                     \
    {   _Pragma("unroll")                                              \
        for (int r_ = 0; r_ < 4; ++r_) {                               \
            float u_ = fmaf(4.8828125e-4f, CR[rt][r_], HH[rt][r_]);    \
            if (u_ > bu[rt][r_]) { bu[rt][r_] = u_; bi[rt][r_] = (CODE); } } }

    half8 C0, C1, C2, C3, D0, D1, D2, D3;
    float ev0, ev1;
    f32x4 hhA[4], crA[4], hhB[4], crB[4];

    // prologue: tile 0 -> stage A; load tile 1 -> D regs
    LOADB(0, C0, C1, C2, C3, ev0);
#pragma unroll
    for (int rt = 0; rt < 4; ++rt) MFMA_RT(rt, hhA, crA, C0, C1, C2, C3, ev0);
    LOADB(1, D0, D1, D2, D3, ev1);

#pragma unroll 1
    for (int it = 0; it < 15; ++it) {
        // first half: issue MFMA(2it+1) -> stage B, score stage A (tile 2it)
#pragma unroll
        for (int rt = 0; rt < 4; ++rt) {
            MFMA_RT(rt, hhB, crB, D0, D1, D2, D3, ev1);
            SCORE_RT(rt, hhA, crA, (2 * it) * 16 + n);
        }
        LOADB(2 * it + 2, C0, C1, C2, C3, ev0);
        // second half: issue MFMA(2it+2) -> stage A, score stage B (tile 2it+1)
#pragma unroll
        for (int rt = 0; rt < 4; ++rt) {
            MFMA_RT(rt, hhA, crA, C0, C1, C2, C3, ev0);
            SCORE_RT(rt, hhB, crB, (2 * it + 1) * 16 + n);
        }
        LOADB(2 * it + 3, D0, D1, D2, D3, ev1);
    }
    // drain: stage A holds tile 30; D holds B(31)
#pragma unroll
    for (int rt = 0; rt < 4; ++rt) {
        MFMA_RT(rt, hhB, crB, D0, D1, D2, D3, ev1);
        SCORE_RT(rt, hhA, crA, 30 * 16 + n);
    }
#pragma unroll
    for (int rt = 0; rt < 4; ++rt) SCORE_RT(rt, hhB, crB, 31 * 16 + n);

    // ---- cross-lane argmax over the 16 code-columns
#pragma unroll
    for (int mask = 1; mask < 16; mask <<= 1) {
#pragma unroll
        for (int rt = 0; rt < 4; ++rt)
#pragma unroll
            for (int r = 0; r < 4; ++r) {
                float ou = __shfl_xor(bu[rt][r], mask);
                int oi = __shfl_xor(bi[rt][r], mask);
                if (ou > bu[rt][r] || (ou == bu[rt][r] && oi < bi[rt][r])) { bu[rt][r] = ou; bi[rt][r] = oi; }
            }
    }
    if (n == 0) {
#pragma unroll
        for (int rt = 0; rt < 4; ++rt)
#pragma unroll
            for (int r = 0; r < 4; ++r)
                idx_s[w * 64 + rt * 16 + g * 4 + r] = bi[rt][r];   // C-layout row = g*4 + r
    }
    __syncthreads();

    // ---- loss from A-frags (x ~ hi + lo*2^-11): no x re-read. Each (token,dim) counted once.
    float lsum = 0.f;
#pragma unroll
    for (int rt = 0; rt < 4; ++rt) {
        const int gidx = idx_s[w * 64 + rt * 16 + n];
        const float* eq = ET + (size_t)gidx * D_DIM + g * 8;
#pragma unroll
        for (int ks = 0; ks < 2; ++ks) {
            float4 q0 = *(const float4*)(eq + ks * 32);
            float4 q1 = *(const float4*)(eq + ks * 32 + 4);
            float qv[8] = {q0.x, q0.y, q0.z, q0.w, q1.x, q1.y, q1.z, q1.w};
#pragma unroll
            for (int j = 0; j < 8; ++j) {
                float xr = fmaf((float)Alo[rt][ks][j], 4.8828125e-4f, (float)Ahi[rt][ks][j]);
                float dd = qv[j] - xr;
                lsum = fmaf(dd, dd, lsum);
            }
        }
    }
#pragma unroll
    for (int mask = 1; mask < 64; mask <<= 1) lsum += __shfl_xor(lsum, mask);
    if (l == 0) wsum_s[w] = lsum;

    // ---- q-write: coalesced gather from ET (L2-hot)
#pragma unroll
    for (int p = 0; p < 4; ++p) {
        const int tok = p * 128 + (tid >> 2);
        const int part = tid & 3;
        const int gidx = idx_s[tok];
        const size_t qoff = (size_t)(bt0 + tok) * D_DIM + part * 16;
        const float4* ep = (const float4*)(ET + (size_t)gidx * D_DIM + part * 16);
        float4* qp = (float4*)(out_q + qoff);
#pragma unroll
        for (int u = 0; u < 4; ++u) qp[u] = ep[u];
    }
    __syncthreads();
    if (tid == 0) {
        float total = 0.f;
#pragma unroll
        for (int i = 0; i < 8; ++i) total += wsum_s[i];
        atomicAdd(out_loss, total * loss_scale);
    }
}

// =================== round-1 fallback (proven) ===================
#define TOK_TILE 64
#define CHUNK 64
#define NCHUNK (K_CODES / CHUNK)
#define XS_STRIDE (TOK_TILE + 4)

__global__ __launch_bounds__(256, 4) void vq_fb_main(
        const float* __restrict__ x, const float* __restrict__ E,
        float* __restrict__ out_q, float* __restrict__ out_loss, float loss_scale) {
    __shared__ __align__(16) float Xs[D_DIM][XS_STRIDE];
    __shared__ __align__(16) float Es[D_DIM][CHUNK];
    __shared__ float ee_s[K_CODES];
    __shared__ int idx_s[TOK_TILE];
    __shared__ float wsum_s[4];

    const int tid = threadIdx.x;
    const int t0 = blockIdx.x * TOK_TILE;
    const int tx = tid & 15, ty = tid >> 4;
    const int ty4 = ty * 4, tx4 = tx * 4;

#pragma unroll
    for (int it = 0; it < 4; ++it) {
        int tl = it * 16 + (tid >> 4);
        int d0 = (tid & 15) * 4;
        float4 v = *(const float4*)(x + (size_t)(t0 + tl) * D_DIM + d0);
        Xs[d0 + 0][tl] = v.x; Xs[d0 + 1][tl] = v.y; Xs[d0 + 2][tl] = v.z; Xs[d0 + 3][tl] = v.w;
    }
    for (int k = tid; k < K_CODES; k += 256) {
        float s = 0.f;
#pragma unroll
        for (int d = 0; d < D_DIM; ++d) { float v = E[(size_t)d * K_CODES + k]; s = fmaf(v, v, s); }
        ee_s[k] = s;
    }

    float bd[4] = {3.4e38f, 3.4e38f, 3.4e38f, 3.4e38f};
    int bi[4] = {0, 0, 0, 0};

    for (int c = 0; c < NCHUNK; ++c) {
        __syncthreads();
#pragma unroll
        for (int ww = 0; ww < 4; ++ww) {
            int fidx = ww * 256 + tid;
            int d = fidx >> 4, k0 = (fidx & 15) * 4;
            float4 v = *(const float4*)(E + (size_t)d * K_CODES + c * CHUNK + k0);
            *(float4*)&Es[d][k0] = v;
        }
        __syncthreads();
        float acc[4][4] = {};
#pragma unroll
        for (int d = 0; d < D_DIM; ++d) {
            float4 a = *(const float4*)&Xs[d][ty4];
            float4 b = *(const float4*)&Es[d][tx4];
            acc[0][0] = fmaf(a.x, b.x, acc[0][0]); acc[0][1] = fmaf(a.x, b.y, acc[0][1]);
            acc[0][2] = fmaf(a.x, b.z, acc[0][2]); acc[0][3] = fmaf(a.x, b.w, acc[0][3]);
            acc[1][0] = fmaf(a.y, b.x, acc[1][0]); acc[1][1] = fmaf(a.y, b.y, acc[1][1]);
            acc[1][2] = fmaf(a.y, b.z, acc[1][2]); acc[1][3] = fmaf(a.y, b.w, acc[1][3]);
            acc[2][0] = fmaf(a.z, b.x, acc[2][0]); acc[2][1] = fmaf(a.z, b.y, acc[2][1]);
            acc[2][2] = fmaf(a.z, b.z, acc[2][2]); acc[2][3] = fmaf(a.z, b.w, acc[2][3]);
            acc[3][0] = fmaf(a.w, b.x, acc[3][0]); acc[3][1] = fmaf(a.w, b.y, acc[3][1]);
            acc[3][2] = fmaf(a.w, b.z, acc[3][2]); acc[3][3] = fmaf(a.w, b.w, acc[3][3]);
        }
        const int kbase = c * CHUNK + tx4;
#pragma unroll
        for (int i = 0; i < 4; ++i)
#pragma unroll
            for (int j = 0; j < 4; ++j) {
                float s = fmaf(-2.f, acc[i][j], ee_s[kbase + j]);
                if (s < bd[i]) { bd[i] = s; bi[i] = kbase + j; }
            }
    }
#pragma unroll
    for (int mask = 1; mask < 16; mask <<= 1)
#pragma unroll
        for (int i = 0; i < 4; ++i) {
            float od = __shfl_xor(bd[i], mask);
            int oi = __shfl_xor(bi[i], mask);
            if (od < bd[i] || (od == bd[i] && oi < bi[i])) { bd[i] = od; bi[i] = oi; }
        }
    if (tx == 0)
#pragma unroll
        for (int i = 0; i < 4; ++i) idx_s[ty4 + i] = bi[i];
    __syncthreads();

    const int tok = tid >> 2, part = tid & 3;
    const int gidx = idx_s[tok];
    const int gt = t0 + tok;
    float lsum = 0.f;
#pragma unroll
    for (int ww = 0; ww < 4; ++ww) {
        int o = part * 16 + ww * 4;
        float4 qv;
        qv.x = E[(size_t)(o + 0) * K_CODES + gidx];
        qv.y = E[(size_t)(o + 1) * K_CODES + gidx];
        qv.z = E[(size_t)(o + 2) * K_CODES + gidx];
        qv.w = E[(size_t)(o + 3) * K_CODES + gidx];
        float4 xv;
        xv.x = Xs[o + 0][tok]; xv.y = Xs[o + 1][tok]; xv.z = Xs[o + 2][tok]; xv.w = Xs[o + 3][tok];
        float dx = qv.x - xv.x, dy = qv.y - xv.y, dz = qv.z - xv.z, dw = qv.w - xv.w;
        lsum = fmaf(dx, dx, lsum); lsum = fmaf(dy, dy, lsum);
        lsum = fmaf(dz, dz, lsum); lsum = fmaf(dw, dw, lsum);
        *(float4*)(out_q + (size_t)gt * D_DIM + o) = qv;
    }
#pragma unroll
    for (int mask = 1; mask < 64; mask <<= 1) lsum += __shfl_xor(lsum, mask);
    if ((tid & 63) == 0) wsum_s[tid >> 6] = lsum;
    __syncthreads();
    if (tid == 0) atomicAdd(out_loss, (wsum_s[0] + wsum_s[1] + wsum_s[2] + wsum_s[3]) * loss_scale);
}

extern "C" void kernel_launch(void* const* d_in, const int* in_sizes, int n_in,
                              void* d_out, int out_size, void* d_ws, size_t ws_size,
                              hipStream_t stream) {
    const float* x = (const float*)d_in[0];   // [B,T,D] fp32
    const float* E = (const float*)d_in[1];   // [D,K] fp32
    float* out = (float*)d_out;
    const int n_tok = in_sizes[0] / D_DIM;    // 131072
    float* loss_ptr = out + (out_size - 1);
    const float loss_scale = 2.0f / (float)(n_tok * D_DIM);

    hipMemsetAsync(loss_ptr, 0, sizeof(float), stream);

    if (ws_size >= (size_t)WS_NEEDED) {
        float* ee = (float*)((char*)d_ws + WS_EE_OFF);
        float* ET = (float*)((char*)d_ws + WS_ET_OFF);
        _Float16* Bimg = (_Float16*)((char*)d_ws + WS_BIMG_OFF);
        vq3_prep<<<2, 256, 0, stream>>>(E, ee, ET, Bimg);
        vq8_main<<<n_tok / 512, 512, 0, stream>>>(x, ee, ET, Bimg, out, loss_ptr, loss_scale);
    } else {
        vq_fb_main<<<n_tok / TOK_TILE, 256, 0, stream>>>(x, E, out, loss_ptr, loss_scale);
    }
}